// Round 7
// baseline (264.377 us; speedup 1.0000x reference)
//
#include <hip/hip_runtime.h>

#define N_NODES 256
#define F_DIM   16
#define H_DIM   2048
#define P_DIM   16
#define E_EDGES 32768
#define MAGIC   0x5AFE600Du
#define SPIN_CAP (1u << 27)

// ws layout (32-bit words): cntT[65536] (cntT[s*256+d]), deg[256], flagA[256], flagB[256]
//
// Single fused kernel, one block per node, 512 threads (8 waves).
// Algebra: out = A@(x@W)+b == (A@x)@W+b (K collapses 2048->16):
//   g[n][f] = dinv[n]*( sum_s cnt[s][n]*dinv[s]*x[s][f] + dinv[n]*x[n][f] )
//   o[n][h] = sum_f g[n][f]*W[f][h] + b[h]
//   q[n][p] = sum_h o[n][h]*Wq[n][h][p] + bq[n][p]
// Device-side barriers: per-block flags (poison 0xAAAAAAAA != MAGIC -> self-init).
// Grid=256 blocks, 8 waves, 18KB LDS -> all blocks co-resident (no deadlock).
__global__ __launch_bounds__(512) void k_fused(
    const float* __restrict__ x, const int* __restrict__ ei,
    const float* __restrict__ W, const float* __restrict__ b,
    const float* __restrict__ Wq, const float* __restrict__ bq,
    float* __restrict__ qout, float* __restrict__ ws)
{
    float* cntT = ws;                                   // 65536 floats
    float* deg  = ws + 65536;                           // 256 floats
    unsigned int* flagA = (unsigned int*)(ws + 65536 + 256);
    unsigned int* flagB = flagA + 256;

    __shared__ float xlT[F_DIM][N_NODES];   // x transposed: conflict-free gather reads
    __shared__ float dinv[N_NODES];
    __shared__ float g[F_DIM];
    __shared__ float red[8][P_DIM];

    const int n = blockIdx.x;
    const int t = threadIdx.x;

    // ---- phase 0: zero my cntT row (agent-scope stores), stage x; block 0 zeroes deg
    if (t < 256) {
        __hip_atomic_store(&cntT[n * 256 + t], 0.0f,
                           __ATOMIC_RELAXED, __HIP_MEMORY_SCOPE_AGENT);
        if (n == 0)
            __hip_atomic_store(&deg[t], 0.0f,
                               __ATOMIC_RELAXED, __HIP_MEMORY_SCOPE_AGENT);
        const float4* x4 = (const float4*)(x + t * F_DIM);
        float4 a0 = x4[0], a1 = x4[1], a2 = x4[2], a3 = x4[3];
        xlT[0][t]  = a0.x; xlT[1][t]  = a0.y; xlT[2][t]  = a0.z; xlT[3][t]  = a0.w;
        xlT[4][t]  = a1.x; xlT[5][t]  = a1.y; xlT[6][t]  = a1.z; xlT[7][t]  = a1.w;
        xlT[8][t]  = a2.x; xlT[9][t]  = a2.y; xlT[10][t] = a2.z; xlT[11][t] = a2.w;
        xlT[12][t] = a3.x; xlT[13][t] = a3.y; xlT[14][t] = a3.z; xlT[15][t] = a3.w;
    }
    if (t < F_DIM) g[t] = 0.0f;
    __threadfence();            // agent-scope fence: my zero-stores visible
    __syncthreads();
    if (t == 0)
        __hip_atomic_store(&flagA[n], MAGIC, __ATOMIC_RELEASE, __HIP_MEMORY_SCOPE_AGENT);

    // ---- barrier A: wait until ALL rows zeroed
    if (t < 256) {
        unsigned int it = 0;
        while (__hip_atomic_load(&flagA[t], __ATOMIC_ACQUIRE,
                                 __HIP_MEMORY_SCOPE_AGENT) != MAGIC) {
            __builtin_amdgcn_s_sleep(1);
            if (++it > SPIN_CAP) break;   // fail visibly rather than hang
        }
    }
    __syncthreads();
    __threadfence();

    // ---- phase 1: edge-parallel counts; block n owns edges [n*128, n*128+128)
    if (t < 128) {
        int e = n * 128 + t;
        int s = ei[e];
        int d = ei[E_EDGES + e];
        atomicAdd(&cntT[s * 256 + d], 1.0f);   // device-scope
        atomicAdd(&deg[d], 1.0f);
    }
    __threadfence();
    __syncthreads();
    if (t == 0)
        __hip_atomic_store(&flagB[n], MAGIC, __ATOMIC_RELEASE, __HIP_MEMORY_SCOPE_AGENT);

    // ---- barrier B: wait until ALL edge atomics landed
    if (t < 256) {
        unsigned int it = 0;
        while (__hip_atomic_load(&flagB[t], __ATOMIC_ACQUIRE,
                                 __HIP_MEMORY_SCOPE_AGENT) != MAGIC) {
            __builtin_amdgcn_s_sleep(1);
            if (++it > SPIN_CAP) break;
        }
    }
    __syncthreads();
    __threadfence();

    // ---- phase 2: dinv, then g-gather (cnt column n), all agent-scope loads
    if (t < 256) {
        float dv = __hip_atomic_load(&deg[t], __ATOMIC_RELAXED,
                                     __HIP_MEMORY_SCOPE_AGENT);
        dinv[t] = rsqrtf(dv + 1.0f);           // +1 = self-loop
    }
    __syncthreads();
    if (t < 256) {
        float a = __hip_atomic_load(&cntT[t * 256 + n], __ATOMIC_RELAXED,
                                    __HIP_MEMORY_SCOPE_AGENT);
        if (t == n) a += 1.0f;                 // self-loop edge
        a *= dinv[t];
        if (a != 0.0f) {
#pragma unroll
            for (int f = 0; f < F_DIM; ++f)
                atomicAdd(&g[f], a * xlT[f][t]);   // LDS atomics, 16 banks
        }
    }
    __syncthreads();

    const float dn = dinv[n];
    float gr[F_DIM];
#pragma unroll
    for (int f = 0; f < F_DIM; ++f) gr[f] = g[f] * dn;   // LDS broadcast

    // ---- phase 3: o[i] = b[hh] + sum_f gr[f]*W[f][hh], hh = i*512 + t
    float o[4];
#pragma unroll
    for (int i = 0; i < 4; ++i) {
        int hh = i * 512 + t;
        float v = b[hh];
#pragma unroll
        for (int f = 0; f < F_DIM; ++f)
            v += gr[f] * W[f * H_DIM + hh];
        o[i] = v;
    }

    // ---- phase 4: stream Wq[n] (128 KB, coalesced float4 x4 per hh)
    float acc[16];
#pragma unroll
    for (int p = 0; p < 16; ++p) acc[p] = 0.0f;
    const float* Wqn = Wq + (size_t)n * H_DIM * P_DIM;
#pragma unroll
    for (int i = 0; i < 4; ++i) {
        int hh = i * 512 + t;
        float ov = o[i];
        const float4* p4 = (const float4*)(Wqn + (size_t)hh * P_DIM);
        float4 u0 = p4[0], u1 = p4[1], u2 = p4[2], u3 = p4[3];
        acc[0]  += ov * u0.x; acc[1]  += ov * u0.y; acc[2]  += ov * u0.z; acc[3]  += ov * u0.w;
        acc[4]  += ov * u1.x; acc[5]  += ov * u1.y; acc[6]  += ov * u1.z; acc[7]  += ov * u1.w;
        acc[8]  += ov * u2.x; acc[9]  += ov * u2.y; acc[10] += ov * u2.z; acc[11] += ov * u2.w;
        acc[12] += ov * u3.x; acc[13] += ov * u3.y; acc[14] += ov * u3.z; acc[15] += ov * u3.w;
    }

    // ---- reduce: wave butterfly (64 lanes) then cross-wave via LDS
#pragma unroll
    for (int p = 0; p < 16; ++p)
#pragma unroll
        for (int off = 32; off > 0; off >>= 1)
            acc[p] += __shfl_down(acc[p], off, 64);

    const int w = t >> 6, l = t & 63;
    if (l == 0) {
#pragma unroll
        for (int p = 0; p < 16; ++p) red[w][p] = acc[p];
    }
    __syncthreads();
    if (t < P_DIM) {
        float s = red[0][t] + red[1][t] + red[2][t] + red[3][t] +
                  red[4][t] + red[5][t] + red[6][t] + red[7][t] +
                  bq[n * P_DIM + t];
        qout[n * P_DIM + t] = s;
    }
}

extern "C" void kernel_launch(void* const* d_in, const int* in_sizes, int n_in,
                              void* d_out, int out_size, void* d_ws, size_t ws_size,
                              hipStream_t stream) {
    const float* x  = (const float*)d_in[0];  // [256,16]
    const int*   ei = (const int*)d_in[1];    // [2,32768]
    const float* W  = (const float*)d_in[2];  // [16,2048]
    const float* b  = (const float*)d_in[3];  // [2048]
    const float* Wq = (const float*)d_in[4];  // [256,2048,16]
    const float* bq = (const float*)d_in[5];  // [256,16]
    float* qout = (float*)d_out;              // [256,16]
    float* ws   = (float*)d_ws;

    k_fused<<<N_NODES, 512, 0, stream>>>(x, ei, W, b, Wq, bq, qout, ws);
}

// Round 8
// 127.293 us; speedup vs baseline: 2.0769x; 2.0769x over previous
//
#include <hip/hip_runtime.h>

#define N_NODES 256
#define F_DIM   16
#define H_DIM   2048
#define P_DIM   16
#define E_EDGES 32768

// ---------------------------------------------------------------------------
// ONE kernel, one block per node, 512 threads, ZERO cross-block communication.
// Algebra: out = A@(x@W)+b == (A@x)@W+b (K collapses 2048->16):
//   g[n][f] = dinv[n]*( sum_{e:dst=n} dinv[src] x[src][f] + dinv[n] x[n][f] )
//   o[n][h] = sum_f g[n][f] W[f][h] + b[h]
//   q[n][p] = sum_h o[n][h] Wq[n][h][p] + bq[n][p]
// Each block redundantly histograms dst (one int4-vectorized pass, values kept
// in registers) -> dinv; then filters its own in-edges from those registers.
// Redundant work ≈ 33 MB L2 reads + 32K LDS atomics per block — ~2 µs, vs
// ~10 µs per extra graph node + failed 150 µs global-barrier alternative.
// ---------------------------------------------------------------------------
__global__ __launch_bounds__(512) void k_one(
    const float* __restrict__ x, const int* __restrict__ ei,
    const float* __restrict__ W, const float* __restrict__ b,
    const float* __restrict__ Wq, const float* __restrict__ bq,
    float* __restrict__ qout)
{
    __shared__ float xlT[F_DIM][N_NODES];  // x transposed: conflict-free reads
    __shared__ int   degs[N_NODES];
    __shared__ float dinv[N_NODES];
    __shared__ float g[F_DIM];
    __shared__ float red[8][P_DIM];

    const int n = blockIdx.x;
    const int t = threadIdx.x;

    // ---- stage x -> LDS (transposed), zero histogram + g
    if (t < 256) {
        degs[t] = 0;
        const float4* x4 = (const float4*)(x + t * F_DIM);
        float4 a0 = x4[0], a1 = x4[1], a2 = x4[2], a3 = x4[3];
        xlT[0][t]  = a0.x; xlT[1][t]  = a0.y; xlT[2][t]  = a0.z; xlT[3][t]  = a0.w;
        xlT[4][t]  = a1.x; xlT[5][t]  = a1.y; xlT[6][t]  = a1.z; xlT[7][t]  = a1.w;
        xlT[8][t]  = a2.x; xlT[9][t]  = a2.y; xlT[10][t] = a2.z; xlT[11][t] = a2.w;
        xlT[12][t] = a3.x; xlT[13][t] = a3.y; xlT[14][t] = a3.z; xlT[15][t] = a3.w;
    }
    if (t < F_DIM) g[t] = 0.0f;
    __syncthreads();

    // ---- P1: histogram ALL dst into LDS; keep dst values in registers.
    // thread t reads int4 k = t + 512*i (i<16): 32768 edges total, coalesced.
    const int4* dst4 = (const int4*)(ei + E_EDGES);
    int4 dreg[16];
#pragma unroll
    for (int i = 0; i < 16; ++i)
        dreg[i] = dst4[t + 512 * i];
#pragma unroll
    for (int i = 0; i < 16; ++i) {
        atomicAdd(&degs[dreg[i].x], 1);
        atomicAdd(&degs[dreg[i].y], 1);
        atomicAdd(&degs[dreg[i].z], 1);
        atomicAdd(&degs[dreg[i].w], 1);
    }
    __syncthreads();

    // ---- dinv = rsqrt(deg+1)  (+1 self-loop)
    if (t < 256)
        dinv[t] = rsqrtf((float)degs[t] + 1.0f);
    __syncthreads();

    // ---- P2: filter my in-edges from the register copy (~0.25 hits/thread)
    const int* src = ei;
#pragma unroll
    for (int i = 0; i < 16; ++i) {
        int k = t + 512 * i;
#pragma unroll
        for (int j = 0; j < 4; ++j) {
            int dv = (j == 0) ? dreg[i].x : (j == 1) ? dreg[i].y
                   : (j == 2) ? dreg[i].z : dreg[i].w;
            if (dv == n) {
                int s = src[4 * k + j];
                float a = dinv[s];
#pragma unroll
                for (int f = 0; f < F_DIM; ++f)
                    atomicAdd(&g[f], a * xlT[f][s]);
            }
        }
    }
    __syncthreads();

    // ---- gr[f] = (g[f] + dinv[n]*x[n][f]) * dinv[n]
    const float dn = dinv[n];
    float gr[F_DIM];
#pragma unroll
    for (int f = 0; f < F_DIM; ++f)
        gr[f] = (g[f] + dn * xlT[f][n]) * dn;

    // ---- o[i] = b[hh] + sum_f gr[f]*W[f][hh],  hh = i*512 + t (coalesced)
    float o[4];
#pragma unroll
    for (int i = 0; i < 4; ++i) {
        int hh = i * 512 + t;
        float v = b[hh];
#pragma unroll
        for (int f = 0; f < F_DIM; ++f)
            v += gr[f] * W[f * H_DIM + hh];
        o[i] = v;
    }

    // ---- stream Wq[n] (128 KB/block, 4x float4 per hh, coalesced)
    float acc[16];
#pragma unroll
    for (int p = 0; p < 16; ++p) acc[p] = 0.0f;
    const float* Wqn = Wq + (size_t)n * H_DIM * P_DIM;
#pragma unroll
    for (int i = 0; i < 4; ++i) {
        int hh = i * 512 + t;
        float ov = o[i];
        const float4* p4 = (const float4*)(Wqn + (size_t)hh * P_DIM);
        float4 u0 = p4[0], u1 = p4[1], u2 = p4[2], u3 = p4[3];
        acc[0]  += ov * u0.x; acc[1]  += ov * u0.y; acc[2]  += ov * u0.z; acc[3]  += ov * u0.w;
        acc[4]  += ov * u1.x; acc[5]  += ov * u1.y; acc[6]  += ov * u1.z; acc[7]  += ov * u1.w;
        acc[8]  += ov * u2.x; acc[9]  += ov * u2.y; acc[10] += ov * u2.z; acc[11] += ov * u2.w;
        acc[12] += ov * u3.x; acc[13] += ov * u3.y; acc[14] += ov * u3.z; acc[15] += ov * u3.w;
    }

    // ---- wave butterfly (64 lanes) then cross-wave via LDS
#pragma unroll
    for (int p = 0; p < 16; ++p)
#pragma unroll
        for (int off = 32; off > 0; off >>= 1)
            acc[p] += __shfl_down(acc[p], off, 64);

    const int w = t >> 6, l = t & 63;
    if (l == 0) {
#pragma unroll
        for (int p = 0; p < 16; ++p) red[w][p] = acc[p];
    }
    __syncthreads();
    if (t < P_DIM) {
        float s = red[0][t] + red[1][t] + red[2][t] + red[3][t] +
                  red[4][t] + red[5][t] + red[6][t] + red[7][t] +
                  bq[n * P_DIM + t];
        qout[n * P_DIM + t] = s;
    }
}

extern "C" void kernel_launch(void* const* d_in, const int* in_sizes, int n_in,
                              void* d_out, int out_size, void* d_ws, size_t ws_size,
                              hipStream_t stream) {
    const float* x  = (const float*)d_in[0];  // [256,16]
    const int*   ei = (const int*)d_in[1];    // [2,32768]
    const float* W  = (const float*)d_in[2];  // [16,2048]
    const float* b  = (const float*)d_in[3];  // [2048]
    const float* Wq = (const float*)d_in[4];  // [256,2048,16]
    const float* bq = (const float*)d_in[5];  // [256,16]
    float* qout = (float*)d_out;              // [256,16]

    k_one<<<N_NODES, 512, 0, stream>>>(x, ei, W, b, Wq, bq, qout);
}